// Round 9
// baseline (997.273 us; speedup 1.0000x reference)
//
#include <hip/hip_runtime.h>
#include <hip/hip_bf16.h>

// ---------------- problem constants ----------------
#define NTOK 4096   // B*S
#define DIM  2048   // D
#define NEXP 8      // E
#define FDIM 4096   // F
#define NPAIR 8192  // NTOK * K(=2)

typedef __attribute__((ext_vector_type(4))) float     f32x4;
typedef __attribute__((ext_vector_type(8))) short     s16x8;
typedef __attribute__((ext_vector_type(4))) short     s16x4;
typedef __attribute__((ext_vector_type(8))) _Float16  f16x8;
typedef __attribute__((ext_vector_type(4))) _Float16  f16x4;

#define DEVI static __device__ __forceinline__

DEVI void gl2lds(const void* g, void* l) {
  __builtin_amdgcn_global_load_lds((const __attribute__((address_space(1))) unsigned int*)g,
                                   (__attribute__((address_space(3))) unsigned int*)l, 16, 0, 0);
}

DEVI float bf2f(unsigned short s) {
  unsigned int u = ((unsigned int)s) << 16; float f; __builtin_memcpy(&f, &u, 4); return f;
}
DEVI unsigned short f2bf(float f) {
  __hip_bfloat16 h = __float2bfloat16(f); unsigned short s; __builtin_memcpy(&s, &h, 2); return s;
}
DEVI float wredsum(float v) {
#pragma unroll
  for (int o = 32; o > 0; o >>= 1) v += __shfl_xor(v, o);
  return v;
}

// ---------------- LayerNorm + input conversions ----------------
__global__ __launch_bounds__(256) void ln_conv_kernel(
    const float* __restrict__ x, const float* __restrict__ gamma, const float* __restrict__ beta,
    _Float16* __restrict__ xh, _Float16* __restrict__ xl, unsigned short* __restrict__ xbf)
{
  int tok = blockIdx.x;
  int tid = threadIdx.x, lane = tid & 63, wv = tid >> 6;
  const float* xr = x + (size_t)tok * DIM;
  float v[8];
  *(float4*)(v)     = *(const float4*)(xr + tid * 8);
  *(float4*)(v + 4) = *(const float4*)(xr + tid * 8 + 4);
  float s = v[0]+v[1]+v[2]+v[3]+v[4]+v[5]+v[6]+v[7];
  __shared__ float red[4];
  s = wredsum(s);
  if (lane == 0) red[wv] = s;
  __syncthreads();
  float mu = (red[0]+red[1]+red[2]+red[3]) * (1.f / DIM);
  __syncthreads();
  float s2 = 0.f;
#pragma unroll
  for (int j = 0; j < 8; j++) { float d = v[j] - mu; s2 += d * d; }
  s2 = wredsum(s2);
  if (lane == 0) red[wv] = s2;
  __syncthreads();
  float var = (red[0]+red[1]+red[2]+red[3]) * (1.f / DIM);
  float rs = 1.0f / sqrtf(var + 1e-5f);

  float4 g0 = *(const float4*)(gamma + tid*8), g1 = *(const float4*)(gamma + tid*8 + 4);
  float4 b0 = *(const float4*)(beta  + tid*8), b1 = *(const float4*)(beta  + tid*8 + 4);
  float gg[8] = {g0.x,g0.y,g0.z,g0.w,g1.x,g1.y,g1.z,g1.w};
  float bb[8] = {b0.x,b0.y,b0.z,b0.w,b1.x,b1.y,b1.z,b1.w};
  f16x8 vh, vl; s16x8 vb;
#pragma unroll
  for (int j = 0; j < 8; j++) {
    float xn = (v[j] - mu) * rs * gg[j] + bb[j];
    _Float16 h = (_Float16)xn;
    vh[j] = h;
    vl[j] = (_Float16)((xn - (float)h) * 4096.f);
    vb[j] = (short)f2bf(v[j]);
  }
  *(f16x8*)(xh + (size_t)tok*DIM + tid*8) = vh;
  *(f16x8*)(xl + (size_t)tok*DIM + tid*8) = vl;
  *(s16x8*)(xbf + (size_t)tok*DIM + tid*8) = vb;
}

// ---------------- pack B: fp32 [E][R(k)][C(n)] -> bf16 MFMA-fragment chunks ----------------
// Chunk layout: [panel p = e*NTN + n-tile(128)][kt(64)][ks(2)][cn(8)][lane(64)*8bf16] = 1KB chunks.
// Lane l of chunk (p,kt,ks,cn) holds B[n = p_n*128 + cn*16 + (l&15)][k = kt*64 + ks*32 + (l>>4)*8 + j].
__global__ __launch_bounds__(256) void pack_b_kernel(
    const float* __restrict__ src, unsigned short* __restrict__ dst, int R, int C)
{
  int e = blockIdx.z;
  src += (size_t)e * R * C;
  const int NTN = C >> 7, KT = R >> 6;
  __shared__ float tile[64][65];     // [k-local][n-local]
  int k0 = blockIdx.y * 64, c0 = blockIdx.x * 64;
  int tx = threadIdx.x & 15, ty = threadIdx.x >> 4;
#pragma unroll
  for (int i = 0; i < 4; i++) {
    float4 v = *(const float4*)(src + (size_t)(k0 + ty*4 + i) * C + c0 + tx*4);
    tile[ty*4+i][tx*4+0] = v.x; tile[ty*4+i][tx*4+1] = v.y;
    tile[ty*4+i][tx*4+2] = v.z; tile[ty*4+i][tx*4+3] = v.w;
  }
  __syncthreads();
  int nt = c0 >> 7;                  // panel within matrix
  int cnb = (c0 >> 4) & 7;           // first of the 4 n-chunks this block covers
  int kt = blockIdx.y;
  int lane = threadIdx.x & 63, cl = threadIdx.x >> 6;
  size_t pbase = (size_t)((e * NTN + nt) * KT + kt) * 8192;   // ushort units (16 chunks x 512)
#pragma unroll
  for (int i = 0; i < 2; i++) {
    int cidx = cl + i*4;             // 0..7
    int ks = cidx >> 2, cnL = cidx & 3;
    int n_local = (cnb + cnL)*16 - cnb*16 + (lane & 15);      // = cnL*16 + (lane&15) within tile
    int k_local = ks*32 + (lane >> 4)*8;
    s16x8 o;
#pragma unroll
    for (int j = 0; j < 8; j++) o[j] = (short)f2bf(tile[k_local + j][cnL*16 + (lane & 15)]);
    (void)n_local;
    *(s16x8*)(dst + pbase + (size_t)(ks*8 + cnb + cnL)*512 + lane*8) = o;
  }
}

// ---------------- transpose + split: fp32 [R][C] -> fp16 hi [C][R], fp16 lo*4096 [C][R] ----------------
__global__ __launch_bounds__(256) void transpose_f16split_kernel(
    const float* __restrict__ src, _Float16* __restrict__ dh, _Float16* __restrict__ dl, int R, int C)
{
  __shared__ float tile[64][65];
  int r0 = blockIdx.y * 64, c0 = blockIdx.x * 64;
  int tx = threadIdx.x & 15, ty = threadIdx.x >> 4;
#pragma unroll
  for (int i = 0; i < 4; i++) {
    float4 v = *(const float4*)(src + (size_t)(r0 + ty*4 + i) * C + c0 + tx*4);
    tile[ty*4+i][tx*4+0] = v.x; tile[ty*4+i][tx*4+1] = v.y;
    tile[ty*4+i][tx*4+2] = v.z; tile[ty*4+i][tx*4+3] = v.w;
  }
  __syncthreads();
#pragma unroll
  for (int i = 0; i < 4; i++) {
    int c = c0 + ty*4 + i;
    f16x4 oh, ol;
#pragma unroll
    for (int j = 0; j < 4; j++) {
      float f = tile[tx*4+j][ty*4+i];
      _Float16 h = (_Float16)f;
      oh[j] = h;
      ol[j] = (_Float16)((f - (float)h) * 4096.f);
    }
    *(f16x4*)(dh + (size_t)c * R + r0 + tx*4) = oh;
    *(f16x4*)(dl + (size_t)c * R + r0 + tx*4) = ol;
  }
}

// ---------------- router GEMM: h = relu(xn @ rW1 + b1), split fp16 3-product ----------------
#define R_TA 10240  // 128*80
#define R_TB 5120   // 64*80
__global__ __launch_bounds__(256) void router_gemm_kernel(
    const _Float16* __restrict__ Ah, const _Float16* __restrict__ Al,
    const _Float16* __restrict__ Bh, const _Float16* __restrict__ Bl,
    const float* __restrict__ bias, float* __restrict__ Cout)
{
  __shared__ char lds[2*R_TA + 2*R_TB];
  char* lAh = lds;             char* lAl = lds + R_TA;
  char* lBh = lds + 2*R_TA;    char* lBl = lds + 2*R_TA + R_TB;
  const int K = DIM;
  int m0 = blockIdx.y * 128, n0 = blockIdx.x * 64;
  int tid = threadIdx.x, lane = tid & 63, wv = tid >> 6;
  int wm = wv >> 1, wn = wv & 1;

  const char* srcAh[3]; const char* srcAl[3];
  const char* srcBh[2]; const char* srcBl[2];
  {
    int i = 0;
    for (int c = wv; c < 10; c += 4, i++) {
      int doff = c*1024 + lane*16;
      int row = doff / 80; int b = doff - row*80; if (b >= 64) b = 0;
      srcAh[i] = (const char*)(Ah + (size_t)(m0+row)*K) + b;
      srcAl[i] = (const char*)(Al + (size_t)(m0+row)*K) + b;
    }
    i = 0;
    for (int c = wv; c < 5; c += 4, i++) {
      int doff = c*1024 + lane*16;
      int row = doff / 80; int b = doff - row*80; if (b >= 64) b = 0;
      srcBh[i] = (const char*)(Bh + (size_t)(n0+row)*K) + b;
      srcBl[i] = (const char*)(Bl + (size_t)(n0+row)*K) + b;
    }
  }

  f32x4 acc1[4][2], acc2[4][2];
#pragma unroll
  for (int mb = 0; mb < 4; mb++)
#pragma unroll
    for (int nb = 0; nb < 2; nb++) {
      acc1[mb][nb] = (f32x4){0.f,0.f,0.f,0.f};
      acc2[mb][nb] = (f32x4){0.f,0.f,0.f,0.f};
    }

  for (int kt = 0; kt < K/32; kt++) {
    {
      int i = 0;
      for (int c = wv; c < 10; c += 4, i++) {
        gl2lds(srcAh[i], lAh + c*1024);
        gl2lds(srcAl[i], lAl + c*1024);
        srcAh[i] += 64; srcAl[i] += 64;
      }
      i = 0;
      for (int c = wv; c < 5; c += 4, i++) {
        gl2lds(srcBh[i], lBh + c*1024);
        gl2lds(srcBl[i], lBl + c*1024);
        srcBh[i] += 64; srcBl[i] += 64;
      }
    }
    __syncthreads();
    int kb = (lane >> 4) * 16;
    f16x8 ah[4], al[4], bh[2], bl[2];
#pragma unroll
    for (int mb = 0; mb < 4; mb++) {
      int r = wm*64 + mb*16 + (lane & 15);
      ah[mb] = *(const f16x8*)(lAh + r*80 + kb);
      al[mb] = *(const f16x8*)(lAl + r*80 + kb);
    }
#pragma unroll
    for (int nb = 0; nb < 2; nb++) {
      int r = wn*32 + nb*16 + (lane & 15);
      bh[nb] = *(const f16x8*)(lBh + r*80 + kb);
      bl[nb] = *(const f16x8*)(lBl + r*80 + kb);
    }
#pragma unroll
    for (int mb = 0; mb < 4; mb++)
#pragma unroll
      for (int nb = 0; nb < 2; nb++) {
        acc1[mb][nb] = __builtin_amdgcn_mfma_f32_16x16x32_f16(ah[mb], bh[nb], acc1[mb][nb], 0,0,0);
        acc2[mb][nb] = __builtin_amdgcn_mfma_f32_16x16x32_f16(ah[mb], bl[nb], acc2[mb][nb], 0,0,0);
        acc2[mb][nb] = __builtin_amdgcn_mfma_f32_16x16x32_f16(al[mb], bh[nb], acc2[mb][nb], 0,0,0);
      }
    __syncthreads();
  }
#pragma unroll
  for (int mb = 0; mb < 4; mb++)
#pragma unroll
    for (int nb = 0; nb < 2; nb++) {
      int col = n0 + wn*32 + nb*16 + (lane & 15);
      float bv = bias[col];
#pragma unroll
      for (int r = 0; r < 4; r++) {
        int m = m0 + wm*64 + mb*16 + (lane >> 4)*4 + r;
        float hval = acc1[mb][nb][r] + acc2[mb][nb][r] * (1.f/4096.f) + bv;
        Cout[(size_t)m*DIM + col] = fmaxf(hval, 0.f);
      }
    }
}

// ---------------- router logits + softmax + top2 (one WAVE per token, no atomics) ----------------
__global__ __launch_bounds__(256) void router_logits_kernel(
    const float* __restrict__ h, const float* __restrict__ rW2, const float* __restrict__ rb2,
    float* __restrict__ probs,   // [NTOK][8]
    int* __restrict__ eid, float* __restrict__ wts)
{
  int lane = threadIdx.x & 63, wv = threadIdx.x >> 6;
  int tok = blockIdx.x * 4 + wv;
  const float* hr = h + (size_t)tok * DIM;
  float lg[8] = {0,0,0,0,0,0,0,0};
#pragma unroll
  for (int j = 0; j < 8; j++) {
    int k = j * 256 + lane * 4;
    float4 hv = *(const float4*)(hr + k);
    float hv4[4] = {hv.x, hv.y, hv.z, hv.w};
#pragma unroll
    for (int r = 0; r < 4; r++) {
      const float4* w4 = (const float4*)(rW2 + (size_t)(k + r) * NEXP);
      float4 wa = w4[0], wb = w4[1];
      lg[0] += hv4[r]*wa.x; lg[1] += hv4[r]*wa.y; lg[2] += hv4[r]*wa.z; lg[3] += hv4[r]*wa.w;
      lg[4] += hv4[r]*wb.x; lg[5] += hv4[r]*wb.y; lg[6] += hv4[r]*wb.z; lg[7] += hv4[r]*wb.w;
    }
  }
#pragma unroll
  for (int e = 0; e < 8; e++) {
#pragma unroll
    for (int o = 32; o > 0; o >>= 1) lg[e] += __shfl_xor(lg[e], o);
  }
  if (lane == 0) {
    float l[8], p[8];
    float m = -1e30f;
#pragma unroll
    for (int e = 0; e < 8; e++) { l[e] = lg[e] + rb2[e]; m = fmaxf(m, l[e]); }
    float s = 0.f;
#pragma unroll
    for (int e = 0; e < 8; e++) { p[e] = expf(l[e] - m); s += p[e]; }
    float inv = 1.f / s;
#pragma unroll
    for (int e = 0; e < 8; e++) { p[e] *= inv; probs[(size_t)tok*8 + e] = p[e]; }
    int i0 = 0;
#pragma unroll
    for (int e = 1; e < 8; e++) if (p[e] > p[i0]) i0 = e;
    int i1 = (i0 == 0) ? 1 : 0;
#pragma unroll
    for (int e = 0; e < 8; e++) if (e != i0 && p[e] > p[i1]) i1 = e;
    float denom = 1.f / (p[i0] + p[i1]);
    eid[tok*2+0] = i0; eid[tok*2+1] = i1;
    wts[tok*2+0] = p[i0]*denom; wts[tok*2+1] = p[i1]*denom;
  }
}

// ---------------- single-block deterministic counting sort + aux loss ----------------
__global__ __launch_bounds__(256) void router_sort_kernel(
    const int* __restrict__ eid, const float* __restrict__ probs,
    int* __restrict__ cnt, int* __restrict__ basep,
    int* __restrict__ tokenlist, int* __restrict__ pairslot,
    float* __restrict__ aux_out)
{
  __shared__ int hist[256][8];
  __shared__ float wsum[4][8];
  __shared__ int bl[8];
  __shared__ int lcnt[8];
  int t = threadIdx.x, lane = t & 63, wv = t >> 6;

  int me[32];
  {
    const int4* ep = (const int4*)(eid + t * 32);
#pragma unroll
    for (int q = 0; q < 8; q++) {
      int4 v = ep[q];
      me[q*4+0] = v.x; me[q*4+1] = v.y; me[q*4+2] = v.z; me[q*4+3] = v.w;
    }
  }
#pragma unroll
  for (int e = 0; e < 8; e++) {
    int ce = 0;
#pragma unroll
    for (int i = 0; i < 32; i++) ce += (me[i] == e) ? 1 : 0;
    hist[t][e] = ce;
  }

  float part[8] = {0,0,0,0,0,0,0,0};
  for (int i = 0; i < 16; i++) {
    const float4* p4 = (const float4*)(probs + (size_t)(t*16 + i) * 8);
    float4 a = p4[0], b = p4[1];
    part[0]+=a.x; part[1]+=a.y; part[2]+=a.z; part[3]+=a.w;
    part[4]+=b.x; part[5]+=b.y; part[6]+=b.z; part[7]+=b.w;
  }
#pragma unroll
  for (int e = 0; e < 8; e++) {
#pragma unroll
    for (int o = 32; o > 0; o >>= 1) part[e] += __shfl_xor(part[e], o);
  }
  if (lane == 0) {
#pragma unroll
    for (int e = 0; e < 8; e++) wsum[wv][e] = part[e];
  }
  __syncthreads();

  if (t < 8) {
    int running = 0;
    for (int i = 0; i < 256; i++) { int tmp = hist[i][t]; hist[i][t] = running; running += tmp; }
    lcnt[t] = running;
  }
  __syncthreads();
  if (t == 0) {
    int b = 0; float aux = 0.f;
#pragma unroll
    for (int e = 0; e < 8; e++) {
      int ce = lcnt[e];
      bl[e] = b; basep[e] = b; cnt[e] = ce; b += ce;
      float pm = (wsum[0][e]+wsum[1][e]+wsum[2][e]+wsum[3][e]) * (1.f / NTOK);
      aux += pm * logf(pm * 8.f + 1e-9f);
    }
    *aux_out = aux;
  }
  __syncthreads();

#pragma unroll
  for (int i = 0; i < 32; i++) {
    int e = me[i];
    int r = 0;
#pragma unroll
    for (int j = 0; j < i; j++) r += (me[j] == e) ? 1 : 0;
    int slot = bl[e] + hist[t][e] + r;
    int pair = t*32 + i;
    tokenlist[slot] = pair >> 1;
    pairslot[pair] = slot;
  }
}

// ---------------- expert grouped GEMM v7: A-only LDS dbuf (32KB), B fragment-packed in L2 ----------------
// Round-8 diagnosis: v6 was ds_read-BW-bound (5:1 LDS:MFMA -> MfmaUtil 26%). Fix: B never
// touches LDS -- pre-packed fragment chunks read as coalesced global_load_dwordx4 (L2-resident,
// panel pinned to its XCD by the v6 decode). A keeps the proven gl2lds+swizzle dbuf (now 2x16KB).
// MODE 1: Eh = relu(Xg @ We1T + be1)  K=2048 N=4096    MODE 2: Yg = Eh @ We2T + be2  K=4096 N=2048
template<int MODE>
__global__ __launch_bounds__(256) void expert_gemm_v7(
    const unsigned short* __restrict__ Abase,
    const unsigned short* __restrict__ Bpack,   // packed fragment chunks
    const float* __restrict__ bias,             // [E][N]
    unsigned short* __restrict__ Cout,          // [slots][N] bf16
    const int* __restrict__ cnt, const int* __restrict__ basep,
    const int* __restrict__ tokenlist)
{
  const int K = (MODE == 1) ? DIM : FDIM;
  const int N = (MODE == 1) ? FDIM : DIM;
  const int NTN = N / 128;
  const int KT = K / 64;
  __shared__ char lds[32768];   // A double buffer: 2 x 16 KB

  // XCD-aware decode (round-8 proven): panel p contiguous on XCD p%8
  int b = blockIdx.x;
  int low3 = b & 7, t2 = b >> 3;
  int mt = t2 & 31, pHi = t2 >> 5;
  int p = pHi * 8 + low3;
  int e = p / NTN, nt = p % NTN;
  int ne = cnt[e];
  if (mt * 128 >= ne) return;
  int mbase = basep[e] + mt * 128;
  int n0 = nt * 128;

  int tid = threadIdx.x, lane = tid & 63, wv = tid >> 6;
  int wm = wv >> 1, wn = wv & 1;

  // A staging: 16 chunks of 1KB; chunk c = wv + i*4; lane l covers row c*8+(l>>3),
  // swizzled source byte ((l&7)^((l>>3)&7))*16 (rule #21).
  const char* srcA[4];
  int sb = (((lane & 7) ^ ((lane >> 3) & 7)) << 4);
#pragma unroll
  for (int i = 0; i < 4; i++) {
    int c = wv + i*4;
    int row = c*8 + (lane >> 3);
    int slot = mbase + row; if (slot > NPAIR - 1) slot = NPAIR - 1;
    size_t arow = (MODE == 1) ? (size_t)tokenlist[slot] : (size_t)slot;
    srcA[i] = (const char*)(Abase + arow * K) + sb;
  }

  // B packed base for this wave: chunks (p, kt, ks, cn=wn*4+nb), lane*8 ushorts
  const unsigned short* pb = Bpack + (size_t)p * KT * 8192 + (size_t)(wn * 4) * 512 + lane * 8;

  f32x4 acc[4][4];
#pragma unroll
  for (int mb = 0; mb < 4; mb++)
#pragma unroll
    for (int nb = 0; nb < 4; nb++) acc[mb][nb] = (f32x4){0.f,0.f,0.f,0.f};

  // prologue: stage A K-tile 0 into buf0
#pragma unroll
  for (int i = 0; i < 4; i++) gl2lds(srcA[i], lds + (wv + i*4)*1024);
  asm volatile("s_waitcnt vmcnt(0)\n\ts_barrier" ::: "memory");

  int rsw = (lane & 7) << 4;
  int cur = 0;
  for (int kt = 0; kt < KT; kt++) {
    char* cA = lds + cur*16384;
    // issue next A tile's staging into the other buffer
    if (kt + 1 < KT) {
      char* nA = lds + (cur^1)*16384;
      size_t ko = (size_t)(kt + 1) * 128;
#pragma unroll
      for (int i = 0; i < 4; i++) gl2lds(srcA[i] + ko, nA + (wv + i*4)*1024);
    }
    // load all 8 B fragments for this K-tile (coalesced, L2-hot)
    const unsigned short* pk = pb + (size_t)kt * 8192;
    s16x8 bfr[2][4];
#pragma unroll
    for (int ks = 0; ks < 2; ks++)
#pragma unroll
      for (int nb = 0; nb < 4; nb++)
        bfr[ks][nb] = *(const s16x8*)(pk + ks*4096 + nb*512);
    // compute on current A buffer (swizzled reads)
#pragma unroll
    for (int ks = 0; ks < 2; ks++) {
      int kb = (ks*64 + (lane >> 4)*16) ^ rsw;
      s16x8 af[4];
#pragma unroll
      for (int mb = 0; mb < 4; mb++)
        af[mb] = *(const s16x8*)(cA + (wm*64 + mb*16 + (lane & 15))*128 + kb);
#pragma unroll
      for (int mb = 0; mb < 4; mb++)
#pragma unroll
        for (int nb = 0; nb < 4; nb++)
          acc[mb][nb] = __builtin_amdgcn_mfma_f32_16x16x32_bf16(af[mb], bfr[ks][nb], acc[mb][nb], 0,0,0);
    }
    // fused fence + barrier (real compiler fence)
    __builtin_amdgcn_sched_barrier(0);
    asm volatile("s_waitcnt lgkmcnt(0)\n\ts_waitcnt vmcnt(0)\n\ts_barrier" ::: "memory");
    __builtin_amdgcn_sched_barrier(0);
    cur ^= 1;
  }

#pragma unroll
  for (int mb = 0; mb < 4; mb++)
#pragma unroll
    for (int nb = 0; nb < 4; nb++) {
      int col = n0 + wn*64 + nb*16 + (lane & 15);
      float bv = bias[(size_t)e * N + col];
#pragma unroll
      for (int r = 0; r < 4; r++) {
        int mloc = mt*128 + wm*64 + mb*16 + (lane >> 4)*4 + r;
        if (mloc < ne) {
          float v = acc[mb][nb][r] + bv;
          if (MODE == 1) v = fmaxf(v, 0.f);
          Cout[((size_t)basep[e] + mloc) * N + col] = f2bf(v);
        }
      }
    }
}

// ---------------- weighted combine of the two expert outputs per token ----------------
__global__ __launch_bounds__(256) void combine_kernel(
    const unsigned short* __restrict__ Yg, const int* __restrict__ pairslot,
    const float* __restrict__ wts, float* __restrict__ out)
{
  int tok = blockIdx.x, tid = threadIdx.x;
  int s0 = pairslot[tok*2], s1 = pairslot[tok*2+1];
  float w0 = wts[tok*2], w1 = wts[tok*2+1];
  s16x8 a = *(const s16x8*)(Yg + (size_t)s0 * DIM + tid*8);
  s16x8 b = *(const s16x8*)(Yg + (size_t)s1 * DIM + tid*8);
  float o[8];
#pragma unroll
  for (int j = 0; j < 8; j++)
    o[j] = w0 * bf2f((unsigned short)a[j]) + w1 * bf2f((unsigned short)b[j]);
  float* op = out + (size_t)tok * DIM + tid*8;
  float4 o0; o0.x=o[0]; o0.y=o[1]; o0.z=o[2]; o0.w=o[3];
  float4 o1; o1.x=o[4]; o1.y=o[5]; o1.z=o[6]; o1.w=o[7];
  *(float4*)op = o0;
  *(float4*)(op + 4) = o1;
}

// ---------------- host launcher ----------------
extern "C" void kernel_launch(void* const* d_in, const int* in_sizes, int n_in,
                              void* d_out, int out_size, void* d_ws, size_t ws_size,
                              hipStream_t stream)
{
  (void)in_sizes; (void)n_in; (void)out_size; (void)ws_size;
  const float* x    = (const float*)d_in[0];
  const float* ln_g = (const float*)d_in[1];
  const float* ln_b = (const float*)d_in[2];
  const float* rW1  = (const float*)d_in[3];
  const float* rb1  = (const float*)d_in[4];
  const float* rW2  = (const float*)d_in[5];
  const float* rb2  = (const float*)d_in[6];
  const float* We1  = (const float*)d_in[7];
  const float* be1  = (const float*)d_in[8];
  const float* We2  = (const float*)d_in[9];
  const float* be2  = (const float*)d_in[10];
  float* out = (float*)d_out;
  float* aux_out = out + (size_t)NTOK * DIM;

  char* ws = (char*)d_ws;
  size_t off = 0;
  auto alloc = [&](size_t bytes) { char* p = ws + off; off += (bytes + 255) & ~(size_t)255; return p; };

  _Float16* XH   = (_Float16*)alloc((size_t)NTOK * DIM * 2);
  _Float16* XL   = (_Float16*)alloc((size_t)NTOK * DIM * 2);
  unsigned short* XBF = (unsigned short*)alloc((size_t)NTOK * DIM * 2);
  _Float16* RW1H = (_Float16*)alloc((size_t)DIM * DIM * 2);
  _Float16* RW1L = (_Float16*)alloc((size_t)DIM * DIM * 2);
  unsigned short* WET = (unsigned short*)alloc((size_t)NEXP * FDIM * DIM * 2); // packed B1 then B2
  unsigned short* EH  = (unsigned short*)alloc((size_t)(NPAIR + 128) * FDIM * 2);
  char* HY = alloc((size_t)(NPAIR + 128) * DIM * 2 > (size_t)NTOK*DIM*4
                     ? (size_t)(NPAIR + 128) * DIM * 2 : (size_t)NTOK*DIM*4);
  float* H = (float*)HY;                 // router hidden, dead before YG is written
  unsigned short* YG = (unsigned short*)HY;
  float* PROB = (float*)alloc((size_t)NTOK * 8 * 4);
  int* CNT  = (int*)alloc(256);
  int* BASE = CNT + 16;
  int* EID  = (int*)alloc((size_t)NPAIR * 4);
  float* WTS = (float*)alloc((size_t)NPAIR * 4);
  int* PAIRSLOT = (int*)alloc((size_t)NPAIR * 4);
  int* TOKLIST  = (int*)alloc((size_t)(NPAIR + 128) * 4);

  ln_conv_kernel<<<NTOK, 256, 0, stream>>>(x, ln_g, ln_b, XH, XL, XBF);
  transpose_f16split_kernel<<<dim3(DIM/64, DIM/64), 256, 0, stream>>>(rW1, RW1H, RW1L, DIM, DIM);
  // pack We1 [E][D(k)][F(n)] -> fragment chunks
  pack_b_kernel<<<dim3(FDIM/64, DIM/64, NEXP), 256, 0, stream>>>(We1, WET, DIM, FDIM);
  router_gemm_kernel<<<dim3(DIM/64, NTOK/128), 256, 0, stream>>>(XH, XL, RW1H, RW1L, rb1, H);
  router_logits_kernel<<<NTOK/4, 256, 0, stream>>>(H, rW2, rb2, PROB, EID, WTS);
  router_sort_kernel<<<1, 256, 0, stream>>>(EID, PROB, CNT, BASE, TOKLIST, PAIRSLOT, aux_out);
  // GEMM1: panels = 8 * 32 = 256; blocks = 256 * 32 mt = 8192 (1-D, XCD-mapped)
  expert_gemm_v7<1><<<8192, 256, 0, stream>>>(XBF, WET, be1, EH, CNT, BASE, TOKLIST);
  // pack We2 [E][F(k)][D(n)] (reuses WET after GEMM1 is done)
  pack_b_kernel<<<dim3(DIM/64, FDIM/64, NEXP), 256, 0, stream>>>(We2, WET, FDIM, DIM);
  // GEMM2: panels = 8 * 16 = 128; blocks = 128 * 32 = 4096
  expert_gemm_v7<2><<<4096, 256, 0, stream>>>(EH, WET, be2, YG, CNT, BASE, TOKLIST);
  combine_kernel<<<NTOK, 256, 0, stream>>>(YG, PAIRSLOT, WTS, out);
}

// Round 10
// 927.595 us; speedup vs baseline: 1.0751x; 1.0751x over previous
//
#include <hip/hip_runtime.h>
#include <hip/hip_bf16.h>

// ---------------- problem constants ----------------
#define NTOK 4096   // B*S
#define DIM  2048   // D
#define NEXP 8      // E
#define FDIM 4096   // F
#define NPAIR 8192  // NTOK * K(=2)

typedef __attribute__((ext_vector_type(4))) float     f32x4;
typedef __attribute__((ext_vector_type(8))) short     s16x8;
typedef __attribute__((ext_vector_type(4))) short     s16x4;
typedef __attribute__((ext_vector_type(8))) _Float16  f16x8;
typedef __attribute__((ext_vector_type(4))) _Float16  f16x4;

#define DEVI static __device__ __forceinline__

DEVI void gl2lds(const void* g, void* l) {
  __builtin_amdgcn_global_load_lds((const __attribute__((address_space(1))) unsigned int*)g,
                                   (__attribute__((address_space(3))) unsigned int*)l, 16, 0, 0);
}

DEVI float bf2f(unsigned short s) {
  unsigned int u = ((unsigned int)s) << 16; float f; __builtin_memcpy(&f, &u, 4); return f;
}
DEVI unsigned short f2bf(float f) {
  __hip_bfloat16 h = __float2bfloat16(f); unsigned short s; __builtin_memcpy(&s, &h, 2); return s;
}
DEVI float wredsum(float v) {
#pragma unroll
  for (int o = 32; o > 0; o >>= 1) v += __shfl_xor(v, o);
  return v;
}

// ---------------- LayerNorm + input conversions ----------------
__global__ __launch_bounds__(256) void ln_conv_kernel(
    const float* __restrict__ x, const float* __restrict__ gamma, const float* __restrict__ beta,
    _Float16* __restrict__ xh, _Float16* __restrict__ xl, unsigned short* __restrict__ xbf)
{
  int tok = blockIdx.x;
  int tid = threadIdx.x, lane = tid & 63, wv = tid >> 6;
  const float* xr = x + (size_t)tok * DIM;
  float v[8];
  *(float4*)(v)     = *(const float4*)(xr + tid * 8);
  *(float4*)(v + 4) = *(const float4*)(xr + tid * 8 + 4);
  float s = v[0]+v[1]+v[2]+v[3]+v[4]+v[5]+v[6]+v[7];
  __shared__ float red[4];
  s = wredsum(s);
  if (lane == 0) red[wv] = s;
  __syncthreads();
  float mu = (red[0]+red[1]+red[2]+red[3]) * (1.f / DIM);
  __syncthreads();
  float s2 = 0.f;
#pragma unroll
  for (int j = 0; j < 8; j++) { float d = v[j] - mu; s2 += d * d; }
  s2 = wredsum(s2);
  if (lane == 0) red[wv] = s2;
  __syncthreads();
  float var = (red[0]+red[1]+red[2]+red[3]) * (1.f / DIM);
  float rs = 1.0f / sqrtf(var + 1e-5f);

  float4 g0 = *(const float4*)(gamma + tid*8), g1 = *(const float4*)(gamma + tid*8 + 4);
  float4 b0 = *(const float4*)(beta  + tid*8), b1 = *(const float4*)(beta  + tid*8 + 4);
  float gg[8] = {g0.x,g0.y,g0.z,g0.w,g1.x,g1.y,g1.z,g1.w};
  float bb[8] = {b0.x,b0.y,b0.z,b0.w,b1.x,b1.y,b1.z,b1.w};
  f16x8 vh, vl; s16x8 vb;
#pragma unroll
  for (int j = 0; j < 8; j++) {
    float xn = (v[j] - mu) * rs * gg[j] + bb[j];
    _Float16 h = (_Float16)xn;
    vh[j] = h;
    vl[j] = (_Float16)((xn - (float)h) * 4096.f);
    vb[j] = (short)f2bf(v[j]);
  }
  *(f16x8*)(xh + (size_t)tok*DIM + tid*8) = vh;
  *(f16x8*)(xl + (size_t)tok*DIM + tid*8) = vl;
  *(s16x8*)(xbf + (size_t)tok*DIM + tid*8) = vb;
}

// ---------------- transpose + convert: fp32 [R][C] -> bf16 [C][R] (batched z) ----------------
__global__ __launch_bounds__(256) void transpose_bf16_kernel(
    const float* __restrict__ src, unsigned short* __restrict__ dst, int R, int C)
{
  src += (size_t)blockIdx.z * R * C;
  dst += (size_t)blockIdx.z * R * C;
  __shared__ float tile[64][65];
  int r0 = blockIdx.y * 64, c0 = blockIdx.x * 64;
  int tx = threadIdx.x & 15, ty = threadIdx.x >> 4;
#pragma unroll
  for (int i = 0; i < 4; i++) {
    float4 v = *(const float4*)(src + (size_t)(r0 + ty*4 + i) * C + c0 + tx*4);
    tile[ty*4+i][tx*4+0] = v.x; tile[ty*4+i][tx*4+1] = v.y;
    tile[ty*4+i][tx*4+2] = v.z; tile[ty*4+i][tx*4+3] = v.w;
  }
  __syncthreads();
#pragma unroll
  for (int i = 0; i < 4; i++) {
    int c = c0 + ty*4 + i;
    s16x4 o;
    o[0] = (short)f2bf(tile[tx*4+0][ty*4+i]); o[1] = (short)f2bf(tile[tx*4+1][ty*4+i]);
    o[2] = (short)f2bf(tile[tx*4+2][ty*4+i]); o[3] = (short)f2bf(tile[tx*4+3][ty*4+i]);
    *(s16x4*)(dst + (size_t)c * R + r0 + tx*4) = o;
  }
}

// ---------------- transpose + split: fp32 [R][C] -> fp16 hi [C][R], fp16 lo*4096 [C][R] ----------------
__global__ __launch_bounds__(256) void transpose_f16split_kernel(
    const float* __restrict__ src, _Float16* __restrict__ dh, _Float16* __restrict__ dl, int R, int C)
{
  __shared__ float tile[64][65];
  int r0 = blockIdx.y * 64, c0 = blockIdx.x * 64;
  int tx = threadIdx.x & 15, ty = threadIdx.x >> 4;
#pragma unroll
  for (int i = 0; i < 4; i++) {
    float4 v = *(const float4*)(src + (size_t)(r0 + ty*4 + i) * C + c0 + tx*4);
    tile[ty*4+i][tx*4+0] = v.x; tile[ty*4+i][tx*4+1] = v.y;
    tile[ty*4+i][tx*4+2] = v.z; tile[ty*4+i][tx*4+3] = v.w;
  }
  __syncthreads();
#pragma unroll
  for (int i = 0; i < 4; i++) {
    int c = c0 + ty*4 + i;
    f16x4 oh, ol;
#pragma unroll
    for (int j = 0; j < 4; j++) {
      float f = tile[tx*4+j][ty*4+i];
      _Float16 h = (_Float16)f;
      oh[j] = h;
      ol[j] = (_Float16)((f - (float)h) * 4096.f);
    }
    *(f16x4*)(dh + (size_t)c * R + r0 + tx*4) = oh;
    *(f16x4*)(dl + (size_t)c * R + r0 + tx*4) = ol;
  }
}

// ---------------- router GEMM: h = relu(xn @ rW1 + b1), split fp16 3-product ----------------
#define R_TA 10240  // 128*80
#define R_TB 5120   // 64*80
__global__ __launch_bounds__(256) void router_gemm_kernel(
    const _Float16* __restrict__ Ah, const _Float16* __restrict__ Al,
    const _Float16* __restrict__ Bh, const _Float16* __restrict__ Bl,
    const float* __restrict__ bias, float* __restrict__ Cout)
{
  __shared__ char lds[2*R_TA + 2*R_TB];
  char* lAh = lds;             char* lAl = lds + R_TA;
  char* lBh = lds + 2*R_TA;    char* lBl = lds + 2*R_TA + R_TB;
  const int K = DIM;
  int m0 = blockIdx.y * 128, n0 = blockIdx.x * 64;
  int tid = threadIdx.x, lane = tid & 63, wv = tid >> 6;
  int wm = wv >> 1, wn = wv & 1;

  const char* srcAh[3]; const char* srcAl[3];
  const char* srcBh[2]; const char* srcBl[2];
  {
    int i = 0;
    for (int c = wv; c < 10; c += 4, i++) {
      int doff = c*1024 + lane*16;
      int row = doff / 80; int b = doff - row*80; if (b >= 64) b = 0;
      srcAh[i] = (const char*)(Ah + (size_t)(m0+row)*K) + b;
      srcAl[i] = (const char*)(Al + (size_t)(m0+row)*K) + b;
    }
    i = 0;
    for (int c = wv; c < 5; c += 4, i++) {
      int doff = c*1024 + lane*16;
      int row = doff / 80; int b = doff - row*80; if (b >= 64) b = 0;
      srcBh[i] = (const char*)(Bh + (size_t)(n0+row)*K) + b;
      srcBl[i] = (const char*)(Bl + (size_t)(n0+row)*K) + b;
    }
  }

  f32x4 acc1[4][2], acc2[4][2];
#pragma unroll
  for (int mb = 0; mb < 4; mb++)
#pragma unroll
    for (int nb = 0; nb < 2; nb++) {
      acc1[mb][nb] = (f32x4){0.f,0.f,0.f,0.f};
      acc2[mb][nb] = (f32x4){0.f,0.f,0.f,0.f};
    }

  for (int kt = 0; kt < K/32; kt++) {
    {
      int i = 0;
      for (int c = wv; c < 10; c += 4, i++) {
        gl2lds(srcAh[i], lAh + c*1024);
        gl2lds(srcAl[i], lAl + c*1024);
        srcAh[i] += 64; srcAl[i] += 64;
      }
      i = 0;
      for (int c = wv; c < 5; c += 4, i++) {
        gl2lds(srcBh[i], lBh + c*1024);
        gl2lds(srcBl[i], lBl + c*1024);
        srcBh[i] += 64; srcBl[i] += 64;
      }
    }
    __syncthreads();
    int kb = (lane >> 4) * 16;
    f16x8 ah[4], al[4], bh[2], bl[2];
#pragma unroll
    for (int mb = 0; mb < 4; mb++) {
      int r = wm*64 + mb*16 + (lane & 15);
      ah[mb] = *(const f16x8*)(lAh + r*80 + kb);
      al[mb] = *(const f16x8*)(lAl + r*80 + kb);
    }
#pragma unroll
    for (int nb = 0; nb < 2; nb++) {
      int r = wn*32 + nb*16 + (lane & 15);
      bh[nb] = *(const f16x8*)(lBh + r*80 + kb);
      bl[nb] = *(const f16x8*)(lBl + r*80 + kb);
    }
#pragma unroll
    for (int mb = 0; mb < 4; mb++)
#pragma unroll
      for (int nb = 0; nb < 2; nb++) {
        acc1[mb][nb] = __builtin_amdgcn_mfma_f32_16x16x32_f16(ah[mb], bh[nb], acc1[mb][nb], 0,0,0);
        acc2[mb][nb] = __builtin_amdgcn_mfma_f32_16x16x32_f16(ah[mb], bl[nb], acc2[mb][nb], 0,0,0);
        acc2[mb][nb] = __builtin_amdgcn_mfma_f32_16x16x32_f16(al[mb], bh[nb], acc2[mb][nb], 0,0,0);
      }
    __syncthreads();
  }
#pragma unroll
  for (int mb = 0; mb < 4; mb++)
#pragma unroll
    for (int nb = 0; nb < 2; nb++) {
      int col = n0 + wn*32 + nb*16 + (lane & 15);
      float bv = bias[col];
#pragma unroll
      for (int r = 0; r < 4; r++) {
        int m = m0 + wm*64 + mb*16 + (lane >> 4)*4 + r;
        float hval = acc1[mb][nb][r] + acc2[mb][nb][r] * (1.f/4096.f) + bv;
        Cout[(size_t)m*DIM + col] = fmaxf(hval, 0.f);
      }
    }
}

// ---------------- router logits + softmax + top2 (one WAVE per token, no atomics) ----------------
__global__ __launch_bounds__(256) void router_logits_kernel(
    const float* __restrict__ h, const float* __restrict__ rW2, const float* __restrict__ rb2,
    float* __restrict__ probs,   // [NTOK][8]
    int* __restrict__ eid, float* __restrict__ wts)
{
  int lane = threadIdx.x & 63, wv = threadIdx.x >> 6;
  int tok = blockIdx.x * 4 + wv;
  const float* hr = h + (size_t)tok * DIM;
  float lg[8] = {0,0,0,0,0,0,0,0};
#pragma unroll
  for (int j = 0; j < 8; j++) {
    int k = j * 256 + lane * 4;
    float4 hv = *(const float4*)(hr + k);
    float hv4[4] = {hv.x, hv.y, hv.z, hv.w};
#pragma unroll
    for (int r = 0; r < 4; r++) {
      const float4* w4 = (const float4*)(rW2 + (size_t)(k + r) * NEXP);
      float4 wa = w4[0], wb = w4[1];
      lg[0] += hv4[r]*wa.x; lg[1] += hv4[r]*wa.y; lg[2] += hv4[r]*wa.z; lg[3] += hv4[r]*wa.w;
      lg[4] += hv4[r]*wb.x; lg[5] += hv4[r]*wb.y; lg[6] += hv4[r]*wb.z; lg[7] += hv4[r]*wb.w;
    }
  }
#pragma unroll
  for (int e = 0; e < 8; e++) {
#pragma unroll
    for (int o = 32; o > 0; o >>= 1) lg[e] += __shfl_xor(lg[e], o);
  }
  if (lane == 0) {
    float l[8], p[8];
    float m = -1e30f;
#pragma unroll
    for (int e = 0; e < 8; e++) { l[e] = lg[e] + rb2[e]; m = fmaxf(m, l[e]); }
    float s = 0.f;
#pragma unroll
    for (int e = 0; e < 8; e++) { p[e] = expf(l[e] - m); s += p[e]; }
    float inv = 1.f / s;
#pragma unroll
    for (int e = 0; e < 8; e++) { p[e] *= inv; probs[(size_t)tok*8 + e] = p[e]; }
    int i0 = 0;
#pragma unroll
    for (int e = 1; e < 8; e++) if (p[e] > p[i0]) i0 = e;
    int i1 = (i0 == 0) ? 1 : 0;
#pragma unroll
    for (int e = 0; e < 8; e++) if (e != i0 && p[e] > p[i1]) i1 = e;
    float denom = 1.f / (p[i0] + p[i1]);
    eid[tok*2+0] = i0; eid[tok*2+1] = i1;
    wts[tok*2+0] = p[i0]*denom; wts[tok*2+1] = p[i1]*denom;
  }
}

// ---------------- single-block deterministic counting sort + aux loss ----------------
__global__ __launch_bounds__(256) void router_sort_kernel(
    const int* __restrict__ eid, const float* __restrict__ probs,
    int* __restrict__ cnt, int* __restrict__ basep,
    int* __restrict__ tokenlist, int* __restrict__ pairslot,
    float* __restrict__ aux_out)
{
  __shared__ int hist[256][8];
  __shared__ float wsum[4][8];
  __shared__ int bl[8];
  __shared__ int lcnt[8];
  int t = threadIdx.x, lane = t & 63, wv = t >> 6;

  int me[32];
  {
    const int4* ep = (const int4*)(eid + t * 32);
#pragma unroll
    for (int q = 0; q < 8; q++) {
      int4 v = ep[q];
      me[q*4+0] = v.x; me[q*4+1] = v.y; me[q*4+2] = v.z; me[q*4+3] = v.w;
    }
  }
#pragma unroll
  for (int e = 0; e < 8; e++) {
    int ce = 0;
#pragma unroll
    for (int i = 0; i < 32; i++) ce += (me[i] == e) ? 1 : 0;
    hist[t][e] = ce;
  }

  float part[8] = {0,0,0,0,0,0,0,0};
  for (int i = 0; i < 16; i++) {
    const float4* p4 = (const float4*)(probs + (size_t)(t*16 + i) * 8);
    float4 a = p4[0], b = p4[1];
    part[0]+=a.x; part[1]+=a.y; part[2]+=a.z; part[3]+=a.w;
    part[4]+=b.x; part[5]+=b.y; part[6]+=b.z; part[7]+=b.w;
  }
#pragma unroll
  for (int e = 0; e < 8; e++) {
#pragma unroll
    for (int o = 32; o > 0; o >>= 1) part[e] += __shfl_xor(part[e], o);
  }
  if (lane == 0) {
#pragma unroll
    for (int e = 0; e < 8; e++) wsum[wv][e] = part[e];
  }
  __syncthreads();

  if (t < 8) {
    int running = 0;
    for (int i = 0; i < 256; i++) { int tmp = hist[i][t]; hist[i][t] = running; running += tmp; }
    lcnt[t] = running;
  }
  __syncthreads();
  if (t == 0) {
    int b = 0; float aux = 0.f;
#pragma unroll
    for (int e = 0; e < 8; e++) {
      int ce = lcnt[e];
      bl[e] = b; basep[e] = b; cnt[e] = ce; b += ce;
      float pm = (wsum[0][e]+wsum[1][e]+wsum[2][e]+wsum[3][e]) * (1.f / NTOK);
      aux += pm * logf(pm * 8.f + 1e-9f);
    }
    *aux_out = aux;
  }
  __syncthreads();

#pragma unroll
  for (int i = 0; i < 32; i++) {
    int e = me[i];
    int r = 0;
#pragma unroll
    for (int j = 0; j < i; j++) r += (me[j] == e) ? 1 : 0;
    int slot = bl[e] + hist[t][e] + r;
    int pair = t*32 + i;
    tokenlist[slot] = pair >> 1;
    pairslot[pair] = slot;
  }
}

// ---------------- expert grouped GEMM v8: 256x256, 8 waves, 128KB static LDS dbuf, counted vmcnt ----------------
// Round-9 lesson: LDS-read-BW-bound needs a BIGGER per-wave tile (128x64 -> 0.75x reads/FLOP)
// and per-K-tile compute long enough (~2160 cyc) that depth-2 prefetch with COUNTED vmcnt(8)
// fully hides HBM latency (v3's drain-0 exposed it). m201 geometry, simple 2-barrier schedule.
// Swizzle = proven 128B-row involution (0 conflicts). XCD panel decode kept (r8).
// MODE 1: Eh = relu(Xg @ We1T + be1)  K=2048 N=4096    MODE 2: Yg = Eh @ We2T + be2  K=4096 N=2048
template<int MODE>
__global__ __launch_bounds__(512) void expert_gemm_v8(
    const unsigned short* __restrict__ Abase,
    const unsigned short* __restrict__ Bbase,   // [E][N][K] bf16
    const float* __restrict__ bias,             // [E][N]
    unsigned short* __restrict__ Cout,          // [slots][N] bf16
    const int* __restrict__ cnt, const int* __restrict__ basep,
    const int* __restrict__ tokenlist)
{
  const int K = (MODE == 1) ? DIM : FDIM;
  const int N = (MODE == 1) ? FDIM : DIM;
  const int NTN = N / 256;
  __shared__ char lds[131072];   // 2 x (A 32KB + B 32KB)

  // XCD-aware decode: panel p contiguous on XCD p%8
  int b = blockIdx.x;
  int low3 = b & 7, t2 = b >> 3;
  int mt = t2 & 31, pHi = t2 >> 5;
  int p = pHi * 8 + low3;
  int e = p / NTN, nt = p % NTN;
  int ne = cnt[e];
  if (mt * 256 >= ne) return;
  int mbase = basep[e] + mt * 256;
  int n0 = nt * 256;

  int tid = threadIdx.x, lane = tid & 63, wv = tid >> 6;   // 8 waves
  int wm = wv >> 2, wn = wv & 3;                           // 2(M) x 4(N)

  // staging: A tile 256x64 = 32 chunks of 1KB; same for B. thread's chunks: c = wv + i*8.
  // lane l covers row c*8 + (l>>3), swizzled source byte ((l&7)^((l>>3)&7))*16 (rule #21).
  const char* srcA[4]; const char* srcB[4];
  int sb = (((lane & 7) ^ ((lane >> 3) & 7)) << 4);
#pragma unroll
  for (int i = 0; i < 4; i++) {
    int c = wv + i*8;
    int row = c*8 + (lane >> 3);           // 0..255
    int slot = mbase + row; if (slot > NPAIR - 1) slot = NPAIR - 1;
    size_t arow = (MODE == 1) ? (size_t)tokenlist[slot] : (size_t)slot;
    srcA[i] = (const char*)(Abase + arow * K) + sb;
    srcB[i] = (const char*)(Bbase + ((size_t)e * N + n0 + row) * K) + sb;
  }

  f32x4 acc[8][4];
#pragma unroll
  for (int mb = 0; mb < 8; mb++)
#pragma unroll
    for (int nb = 0; nb < 4; nb++) acc[mb][nb] = (f32x4){0.f,0.f,0.f,0.f};

  // prologue: issue stage 0 into buf0 (8 gl2lds per thread)
#pragma unroll
  for (int i = 0; i < 4; i++) {
    gl2lds(srcA[i], lds + (wv + i*8)*1024);
    gl2lds(srcB[i], lds + 32768 + (wv + i*8)*1024);
  }

  const int NT = K / 64;
  int rsw = (lane & 7) << 4;
  for (int kt = 0; kt < NT; kt++) {
    int cur = kt & 1;
    char* cbuf = lds + cur*65536;
    // issue next stage into the other buffer, then COUNTED wait: my stage-kt 8 ops done,
    // stage-(kt+1)'s 8 may stay in flight across the barrier (T4: never drain to 0 mid-loop).
    if (kt + 1 < NT) {
      char* nbuf = lds + (cur^1)*65536;
      size_t ko = (size_t)(kt + 1) * 128;
#pragma unroll
      for (int i = 0; i < 4; i++) {
        gl2lds(srcA[i] + ko, nbuf + (wv + i*8)*1024);
        gl2lds(srcB[i] + ko, nbuf + 32768 + (wv + i*8)*1024);
      }
      asm volatile("s_waitcnt vmcnt(8)\n\ts_barrier" ::: "memory");
    } else {
      asm volatile("s_waitcnt vmcnt(0)\n\ts_barrier" ::: "memory");
    }
    // compute on current buffer (swizzled reads; compiler inserts fine-grained lgkmcnt)
#pragma unroll
    for (int ks = 0; ks < 2; ks++) {
      int kb = (ks*64 + (lane >> 4)*16) ^ rsw;
      s16x8 af[8], bf[4];
#pragma unroll
      for (int nb = 0; nb < 4; nb++)
        bf[nb] = *(const s16x8*)(cbuf + 32768 + (wn*64 + nb*16 + (lane & 15))*128 + kb);
#pragma unroll
      for (int mb = 0; mb < 8; mb++)
        af[mb] = *(const s16x8*)(cbuf + (wm*128 + mb*16 + (lane & 15))*128 + kb);
#pragma unroll
      for (int mb = 0; mb < 8; mb++)
#pragma unroll
        for (int nb = 0; nb < 4; nb++)
          acc[mb][nb] = __builtin_amdgcn_mfma_f32_16x16x32_bf16(af[mb], bf[nb], acc[mb][nb], 0,0,0);
    }
    // WAR protection: my LDS reads done before anyone overwrites this buffer next iter.
    __builtin_amdgcn_sched_barrier(0);
    asm volatile("s_waitcnt lgkmcnt(0)\n\ts_barrier" ::: "memory");
    __builtin_amdgcn_sched_barrier(0);
  }

#pragma unroll
  for (int mb = 0; mb < 8; mb++)
#pragma unroll
    for (int nb = 0; nb < 4; nb++) {
      int col = n0 + wn*64 + nb*16 + (lane & 15);
      float bv = bias[(size_t)e * N + col];
#pragma unroll
      for (int r = 0; r < 4; r++) {
        int mloc = mt*256 + wm*128 + mb*16 + (lane >> 4)*4 + r;
        if (mloc < ne) {
          float v = acc[mb][nb][r] + bv;
          if (MODE == 1) v = fmaxf(v, 0.f);
          Cout[((size_t)basep[e] + mloc) * N + col] = f2bf(v);
        }
      }
    }
}

// ---------------- weighted combine of the two expert outputs per token ----------------
__global__ __launch_bounds__(256) void combine_kernel(
    const unsigned short* __restrict__ Yg, const int* __restrict__ pairslot,
    const float* __restrict__ wts, float* __restrict__ out)
{
  int tok = blockIdx.x, tid = threadIdx.x;
  int s0 = pairslot[tok*2], s1 = pairslot[tok*2+1];
  float w0 = wts[tok*2], w1 = wts[tok*2+1];
  s16x8 a = *(const s16x8*)(Yg + (size_t)s0 * DIM + tid*8);
  s16x8 b = *(const s16x8*)(Yg + (size_t)s1 * DIM + tid*8);
  float o[8];
#pragma unroll
  for (int j = 0; j < 8; j++)
    o[j] = w0 * bf2f((unsigned short)a[j]) + w1 * bf2f((unsigned short)b[j]);
  float* op = out + (size_t)tok * DIM + tid*8;
  float4 o0; o0.x=o[0]; o0.y=o[1]; o0.z=o[2]; o0.w=o[3];
  float4 o1; o1.x=o[4]; o1.y=o[5]; o1.z=o[6]; o1.w=o[7];
  *(float4*)op = o0;
  *(float4*)(op + 4) = o1;
}

// ---------------- host launcher ----------------
extern "C" void kernel_launch(void* const* d_in, const int* in_sizes, int n_in,
                              void* d_out, int out_size, void* d_ws, size_t ws_size,
                              hipStream_t stream)
{
  (void)in_sizes; (void)n_in; (void)out_size; (void)ws_size;
  const float* x    = (const float*)d_in[0];
  const float* ln_g = (const float*)d_in[1];
  const float* ln_b = (const float*)d_in[2];
  const float* rW1  = (const float*)d_in[3];
  const float* rb1  = (const float*)d_in[4];
  const float* rW2  = (const float*)d_in[5];
  const float* rb2  = (const float*)d_in[6];
  const float* We1  = (const float*)d_in[7];
  const float* be1  = (const float*)d_in[8];
  const float* We2  = (const float*)d_in[9];
  const float* be2  = (const float*)d_in[10];
  float* out = (float*)d_out;
  float* aux_out = out + (size_t)NTOK * DIM;

  char* ws = (char*)d_ws;
  size_t off = 0;
  auto alloc = [&](size_t bytes) { char* p = ws + off; off += (bytes + 255) & ~(size_t)255; return p; };

  _Float16* XH   = (_Float16*)alloc((size_t)NTOK * DIM * 2);
  _Float16* XL   = (_Float16*)alloc((size_t)NTOK * DIM * 2);
  unsigned short* XBF = (unsigned short*)alloc((size_t)NTOK * DIM * 2);
  _Float16* RW1H = (_Float16*)alloc((size_t)DIM * DIM * 2);
  _Float16* RW1L = (_Float16*)alloc((size_t)DIM * DIM * 2);
  unsigned short* WET = (unsigned short*)alloc((size_t)NEXP * FDIM * DIM * 2); // We1T then We2T
  unsigned short* EH  = (unsigned short*)alloc((size_t)(NPAIR + 512) * FDIM * 2);
  char* HY = alloc((size_t)(NPAIR + 512) * DIM * 2 > (size_t)NTOK*DIM*4
                     ? (size_t)(NPAIR + 512) * DIM * 2 : (size_t)NTOK*DIM*4);
  float* H = (float*)HY;                 // router hidden, dead before YG is written
  unsigned short* YG = (unsigned short*)HY;
  float* PROB = (float*)alloc((size_t)NTOK * 8 * 4);
  int* CNT  = (int*)alloc(256);
  int* BASE = CNT + 16;
  int* EID  = (int*)alloc((size_t)NPAIR * 4);
  float* WTS = (float*)alloc((size_t)NPAIR * 4);
  int* PAIRSLOT = (int*)alloc((size_t)NPAIR * 4);
  int* TOKLIST  = (int*)alloc((size_t)(NPAIR + 512) * 4);

  ln_conv_kernel<<<NTOK, 256, 0, stream>>>(x, ln_g, ln_b, XH, XL, XBF);
  transpose_f16split_kernel<<<dim3(DIM/64, DIM/64), 256, 0, stream>>>(rW1, RW1H, RW1L, DIM, DIM);
  // We1 [E][D][F] -> We1T [E][F][D]
  transpose_bf16_kernel<<<dim3(FDIM/64, DIM/64, NEXP), 256, 0, stream>>>(We1, WET, DIM, FDIM);
  router_gemm_kernel<<<dim3(DIM/64, NTOK/128), 256, 0, stream>>>(XH, XL, RW1H, RW1L, rb1, H);
  router_logits_kernel<<<NTOK/4, 256, 0, stream>>>(H, rW2, rb2, PROB, EID, WTS);
  router_sort_kernel<<<1, 256, 0, stream>>>(EID, PROB, CNT, BASE, TOKLIST, PAIRSLOT, aux_out);
  // GEMM1: panels = 8 experts * 16 n-tiles = 128; blocks = 128 * 32 mt = 4096 (1-D, XCD-mapped)
  expert_gemm_v8<1><<<4096, 512, 0, stream>>>(XBF, WET, be1, EH, CNT, BASE, TOKLIST);
  // We2 [E][F][D] -> We2T [E][D][F]  (reuses WET after GEMM1 is done)
  transpose_bf16_kernel<<<dim3(DIM/64, FDIM/64, NEXP), 256, 0, stream>>>(We2, WET, FDIM, DIM);
  // GEMM2: panels = 8 * 8 = 64; blocks = 64 * 32 = 2048
  expert_gemm_v8<2><<<2048, 512, 0, stream>>>(EH, WET, be2, YG, CNT, BASE, TOKLIST);
  combine_kernel<<<NTOK, 256, 0, stream>>>(YG, PAIRSLOT, WTS, out);
}

// Round 11
// 805.585 us; speedup vs baseline: 1.2379x; 1.1515x over previous
//
#include <hip/hip_runtime.h>
#include <hip/hip_bf16.h>

// ---------------- problem constants ----------------
#define NTOK 4096   // B*S
#define DIM  2048   // D
#define NEXP 8      // E
#define FDIM 4096   // F
#define NPAIR 8192  // NTOK * K(=2)

typedef __attribute__((ext_vector_type(4))) float     f32x4;
typedef __attribute__((ext_vector_type(8))) short     s16x8;
typedef __attribute__((ext_vector_type(4))) short     s16x4;
typedef __attribute__((ext_vector_type(8))) _Float16  f16x8;
typedef __attribute__((ext_vector_type(4))) _Float16  f16x4;

#define DEVI static __device__ __forceinline__

DEVI void gl2lds(const void* g, void* l) {
  __builtin_amdgcn_global_load_lds((const __attribute__((address_space(1))) unsigned int*)g,
                                   (__attribute__((address_space(3))) unsigned int*)l, 16, 0, 0);
}

DEVI float bf2f(unsigned short s) {
  unsigned int u = ((unsigned int)s) << 16; float f; __builtin_memcpy(&f, &u, 4); return f;
}
DEVI unsigned short f2bf(float f) {
  __hip_bfloat16 h = __float2bfloat16(f); unsigned short s; __builtin_memcpy(&s, &h, 2); return s;
}
DEVI float wredsum(float v) {
#pragma unroll
  for (int o = 32; o > 0; o >>= 1) v += __shfl_xor(v, o);
  return v;
}

// ---------------- LayerNorm + input conversions ----------------
__global__ __launch_bounds__(256) void ln_conv_kernel(
    const float* __restrict__ x, const float* __restrict__ gamma, const float* __restrict__ beta,
    _Float16* __restrict__ xh, _Float16* __restrict__ xl, unsigned short* __restrict__ xbf)
{
  int tok = blockIdx.x;
  int tid = threadIdx.x, lane = tid & 63, wv = tid >> 6;
  const float* xr = x + (size_t)tok * DIM;
  float v[8];
  *(float4*)(v)     = *(const float4*)(xr + tid * 8);
  *(float4*)(v + 4) = *(const float4*)(xr + tid * 8 + 4);
  float s = v[0]+v[1]+v[2]+v[3]+v[4]+v[5]+v[6]+v[7];
  __shared__ float red[4];
  s = wredsum(s);
  if (lane == 0) red[wv] = s;
  __syncthreads();
  float mu = (red[0]+red[1]+red[2]+red[3]) * (1.f / DIM);
  __syncthreads();
  float s2 = 0.f;
#pragma unroll
  for (int j = 0; j < 8; j++) { float d = v[j] - mu; s2 += d * d; }
  s2 = wredsum(s2);
  if (lane == 0) red[wv] = s2;
  __syncthreads();
  float var = (red[0]+red[1]+red[2]+red[3]) * (1.f / DIM);
  float rs = 1.0f / sqrtf(var + 1e-5f);

  float4 g0 = *(const float4*)(gamma + tid*8), g1 = *(const float4*)(gamma + tid*8 + 4);
  float4 b0 = *(const float4*)(beta  + tid*8), b1 = *(const float4*)(beta  + tid*8 + 4);
  float gg[8] = {g0.x,g0.y,g0.z,g0.w,g1.x,g1.y,g1.z,g1.w};
  float bb[8] = {b0.x,b0.y,b0.z,b0.w,b1.x,b1.y,b1.z,b1.w};
  f16x8 vh, vl; s16x8 vb;
#pragma unroll
  for (int j = 0; j < 8; j++) {
    float xn = (v[j] - mu) * rs * gg[j] + bb[j];
    _Float16 h = (_Float16)xn;
    vh[j] = h;
    vl[j] = (_Float16)((xn - (float)h) * 4096.f);
    vb[j] = (short)f2bf(v[j]);
  }
  *(f16x8*)(xh + (size_t)tok*DIM + tid*8) = vh;
  *(f16x8*)(xl + (size_t)tok*DIM + tid*8) = vl;
  *(s16x8*)(xbf + (size_t)tok*DIM + tid*8) = vb;
}

// ---------------- transpose + convert: fp32 [R][C] -> bf16 [C][R] (batched z) ----------------
__global__ __launch_bounds__(256) void transpose_bf16_kernel(
    const float* __restrict__ src, unsigned short* __restrict__ dst, int R, int C)
{
  src += (size_t)blockIdx.z * R * C;
  dst += (size_t)blockIdx.z * R * C;
  __shared__ float tile[64][65];
  int r0 = blockIdx.y * 64, c0 = blockIdx.x * 64;
  int tx = threadIdx.x & 15, ty = threadIdx.x >> 4;
#pragma unroll
  for (int i = 0; i < 4; i++) {
    float4 v = *(const float4*)(src + (size_t)(r0 + ty*4 + i) * C + c0 + tx*4);
    tile[ty*4+i][tx*4+0] = v.x; tile[ty*4+i][tx*4+1] = v.y;
    tile[ty*4+i][tx*4+2] = v.z; tile[ty*4+i][tx*4+3] = v.w;
  }
  __syncthreads();
#pragma unroll
  for (int i = 0; i < 4; i++) {
    int c = c0 + ty*4 + i;
    s16x4 o;
    o[0] = (short)f2bf(tile[tx*4+0][ty*4+i]); o[1] = (short)f2bf(tile[tx*4+1][ty*4+i]);
    o[2] = (short)f2bf(tile[tx*4+2][ty*4+i]); o[3] = (short)f2bf(tile[tx*4+3][ty*4+i]);
    *(s16x4*)(dst + (size_t)c * R + r0 + tx*4) = o;
  }
}

// ---------------- transpose + split: fp32 [R][C] -> fp16 hi [C][R], fp16 lo*4096 [C][R] ----------------
__global__ __launch_bounds__(256) void transpose_f16split_kernel(
    const float* __restrict__ src, _Float16* __restrict__ dh, _Float16* __restrict__ dl, int R, int C)
{
  __shared__ float tile[64][65];
  int r0 = blockIdx.y * 64, c0 = blockIdx.x * 64;
  int tx = threadIdx.x & 15, ty = threadIdx.x >> 4;
#pragma unroll
  for (int i = 0; i < 4; i++) {
    float4 v = *(const float4*)(src + (size_t)(r0 + ty*4 + i) * C + c0 + tx*4);
    tile[ty*4+i][tx*4+0] = v.x; tile[ty*4+i][tx*4+1] = v.y;
    tile[ty*4+i][tx*4+2] = v.z; tile[ty*4+i][tx*4+3] = v.w;
  }
  __syncthreads();
#pragma unroll
  for (int i = 0; i < 4; i++) {
    int c = c0 + ty*4 + i;
    f16x4 oh, ol;
#pragma unroll
    for (int j = 0; j < 4; j++) {
      float f = tile[tx*4+j][ty*4+i];
      _Float16 h = (_Float16)f;
      oh[j] = h;
      ol[j] = (_Float16)((f - (float)h) * 4096.f);
    }
    *(f16x4*)(dh + (size_t)c * R + r0 + tx*4) = oh;
    *(f16x4*)(dl + (size_t)c * R + r0 + tx*4) = ol;
  }
}

// ---------------- router GEMM v2: h = relu(xn @ rW1 + b1), split fp16 3-product, LDS dbuf ----------------
// Same pad-80 layout/staging as the validated router (r3/r5), plus the v3-proven double-buffer:
// stage(kt+1) into other buffer while computing kt; fused asm fence+barrier (real compiler fence).
#define R_TA 10240  // 128*80
#define R_TB 5120   // 64*80
#define R_BUF 30720 // R_TA*2 + R_TB*2
__global__ __launch_bounds__(256) void router_gemm_kernel(
    const _Float16* __restrict__ Ah, const _Float16* __restrict__ Al,
    const _Float16* __restrict__ Bh, const _Float16* __restrict__ Bl,
    const float* __restrict__ bias, float* __restrict__ Cout)
{
  __shared__ char lds[2 * R_BUF];
  const int K = DIM;
  int m0 = blockIdx.y * 128, n0 = blockIdx.x * 64;
  int tid = threadIdx.x, lane = tid & 63, wv = tid >> 6;
  int wm = wv >> 1, wn = wv & 1;

  const char* srcAh[3]; const char* srcAl[3];
  const char* srcBh[2]; const char* srcBl[2];
  {
    int i = 0;
    for (int c = wv; c < 10; c += 4, i++) {
      int doff = c*1024 + lane*16;
      int row = doff / 80; int b = doff - row*80; if (b >= 64) b = 0;
      srcAh[i] = (const char*)(Ah + (size_t)(m0+row)*K) + b;
      srcAl[i] = (const char*)(Al + (size_t)(m0+row)*K) + b;
    }
    i = 0;
    for (int c = wv; c < 5; c += 4, i++) {
      int doff = c*1024 + lane*16;
      int row = doff / 80; int b = doff - row*80; if (b >= 64) b = 0;
      srcBh[i] = (const char*)(Bh + (size_t)(n0+row)*K) + b;
      srcBl[i] = (const char*)(Bl + (size_t)(n0+row)*K) + b;
    }
  }

  // stage K-step kt into buffer `buf`
  auto stage = [&](int kt, int buf) {
    char* base = lds + buf * R_BUF;
    char* lAh = base;           char* lAl = base + R_TA;
    char* lBh = base + 2*R_TA;  char* lBl = base + 2*R_TA + R_TB;
    size_t ko = (size_t)kt * 64;
    int i = 0;
    for (int c = wv; c < 10; c += 4, i++) {
      gl2lds(srcAh[i] + ko, lAh + c*1024);
      gl2lds(srcAl[i] + ko, lAl + c*1024);
    }
    i = 0;
    for (int c = wv; c < 5; c += 4, i++) {
      gl2lds(srcBh[i] + ko, lBh + c*1024);
      gl2lds(srcBl[i] + ko, lBl + c*1024);
    }
  };

  f32x4 acc1[4][2], acc2[4][2];
#pragma unroll
  for (int mb = 0; mb < 4; mb++)
#pragma unroll
    for (int nb = 0; nb < 2; nb++) {
      acc1[mb][nb] = (f32x4){0.f,0.f,0.f,0.f};
      acc2[mb][nb] = (f32x4){0.f,0.f,0.f,0.f};
    }

  // prologue
  stage(0, 0);
  asm volatile("s_waitcnt vmcnt(0)\n\ts_barrier" ::: "memory");

  const int NT = K / 32;
  int cur = 0;
  for (int kt = 0; kt < NT; kt++) {
    char* base = lds + cur * R_BUF;
    char* lAh = base;           char* lAl = base + R_TA;
    char* lBh = base + 2*R_TA;  char* lBl = base + 2*R_TA + R_TB;
    if (kt + 1 < NT) stage(kt + 1, cur ^ 1);

    int kb = (lane >> 4) * 16;
    f16x8 ah[4], al[4], bh[2], bl[2];
#pragma unroll
    for (int mb = 0; mb < 4; mb++) {
      int r = wm*64 + mb*16 + (lane & 15);
      ah[mb] = *(const f16x8*)(lAh + r*80 + kb);
      al[mb] = *(const f16x8*)(lAl + r*80 + kb);
    }
#pragma unroll
    for (int nb = 0; nb < 2; nb++) {
      int r = wn*32 + nb*16 + (lane & 15);
      bh[nb] = *(const f16x8*)(lBh + r*80 + kb);
      bl[nb] = *(const f16x8*)(lBl + r*80 + kb);
    }
#pragma unroll
    for (int mb = 0; mb < 4; mb++)
#pragma unroll
      for (int nb = 0; nb < 2; nb++) {
        acc1[mb][nb] = __builtin_amdgcn_mfma_f32_16x16x32_f16(ah[mb], bh[nb], acc1[mb][nb], 0,0,0);
        acc2[mb][nb] = __builtin_amdgcn_mfma_f32_16x16x32_f16(ah[mb], bl[nb], acc2[mb][nb], 0,0,0);
        acc2[mb][nb] = __builtin_amdgcn_mfma_f32_16x16x32_f16(al[mb], bh[nb], acc2[mb][nb], 0,0,0);
      }
    // fused fence + barrier (v3-proven): my LDS reads done, my stagings landed, block barrier
    __builtin_amdgcn_sched_barrier(0);
    asm volatile("s_waitcnt lgkmcnt(0)\n\ts_waitcnt vmcnt(0)\n\ts_barrier" ::: "memory");
    __builtin_amdgcn_sched_barrier(0);
    cur ^= 1;
  }
#pragma unroll
  for (int mb = 0; mb < 4; mb++)
#pragma unroll
    for (int nb = 0; nb < 2; nb++) {
      int col = n0 + wn*32 + nb*16 + (lane & 15);
      float bv = bias[col];
#pragma unroll
      for (int r = 0; r < 4; r++) {
        int m = m0 + wm*64 + mb*16 + (lane >> 4)*4 + r;
        float hval = acc1[mb][nb][r] + acc2[mb][nb][r] * (1.f/4096.f) + bv;
        Cout[(size_t)m*DIM + col] = fmaxf(hval, 0.f);
      }
    }
}

// ---------------- router logits + softmax + top2 (one WAVE per token, no atomics) ----------------
__global__ __launch_bounds__(256) void router_logits_kernel(
    const float* __restrict__ h, const float* __restrict__ rW2, const float* __restrict__ rb2,
    float* __restrict__ probs,   // [NTOK][8]
    int* __restrict__ eid, float* __restrict__ wts)
{
  int lane = threadIdx.x & 63, wv = threadIdx.x >> 6;
  int tok = blockIdx.x * 4 + wv;
  const float* hr = h + (size_t)tok * DIM;
  float lg[8] = {0,0,0,0,0,0,0,0};
#pragma unroll
  for (int j = 0; j < 8; j++) {
    int k = j * 256 + lane * 4;
    float4 hv = *(const float4*)(hr + k);
    float hv4[4] = {hv.x, hv.y, hv.z, hv.w};
#pragma unroll
    for (int r = 0; r < 4; r++) {
      const float4* w4 = (const float4*)(rW2 + (size_t)(k + r) * NEXP);
      float4 wa = w4[0], wb = w4[1];
      lg[0] += hv4[r]*wa.x; lg[1] += hv4[r]*wa.y; lg[2] += hv4[r]*wa.z; lg[3] += hv4[r]*wa.w;
      lg[4] += hv4[r]*wb.x; lg[5] += hv4[r]*wb.y; lg[6] += hv4[r]*wb.z; lg[7] += hv4[r]*wb.w;
    }
  }
#pragma unroll
  for (int e = 0; e < 8; e++) {
#pragma unroll
    for (int o = 32; o > 0; o >>= 1) lg[e] += __shfl_xor(lg[e], o);
  }
  if (lane == 0) {
    float l[8], p[8];
    float m = -1e30f;
#pragma unroll
    for (int e = 0; e < 8; e++) { l[e] = lg[e] + rb2[e]; m = fmaxf(m, l[e]); }
    float s = 0.f;
#pragma unroll
    for (int e = 0; e < 8; e++) { p[e] = expf(l[e] - m); s += p[e]; }
    float inv = 1.f / s;
#pragma unroll
    for (int e = 0; e < 8; e++) { p[e] *= inv; probs[(size_t)tok*8 + e] = p[e]; }
    int i0 = 0;
#pragma unroll
    for (int e = 1; e < 8; e++) if (p[e] > p[i0]) i0 = e;
    int i1 = (i0 == 0) ? 1 : 0;
#pragma unroll
    for (int e = 0; e < 8; e++) if (e != i0 && p[e] > p[i1]) i1 = e;
    float denom = 1.f / (p[i0] + p[i1]);
    eid[tok*2+0] = i0; eid[tok*2+1] = i1;
    wts[tok*2+0] = p[i0]*denom; wts[tok*2+1] = p[i1]*denom;
  }
}

// ---------------- single-block deterministic counting sort + aux loss ----------------
__global__ __launch_bounds__(256) void router_sort_kernel(
    const int* __restrict__ eid, const float* __restrict__ probs,
    int* __restrict__ cnt, int* __restrict__ basep,
    int* __restrict__ tokenlist, int* __restrict__ pairslot,
    float* __restrict__ aux_out)
{
  __shared__ int hist[256][8];
  __shared__ float wsum[4][8];
  __shared__ int bl[8];
  __shared__ int lcnt[8];
  int t = threadIdx.x, lane = t & 63, wv = t >> 6;

  int me[32];
  {
    const int4* ep = (const int4*)(eid + t * 32);
#pragma unroll
    for (int q = 0; q < 8; q++) {
      int4 v = ep[q];
      me[q*4+0] = v.x; me[q*4+1] = v.y; me[q*4+2] = v.z; me[q*4+3] = v.w;
    }
  }
#pragma unroll
  for (int e = 0; e < 8; e++) {
    int ce = 0;
#pragma unroll
    for (int i = 0; i < 32; i++) ce += (me[i] == e) ? 1 : 0;
    hist[t][e] = ce;
  }

  float part[8] = {0,0,0,0,0,0,0,0};
  for (int i = 0; i < 16; i++) {
    const float4* p4 = (const float4*)(probs + (size_t)(t*16 + i) * 8);
    float4 a = p4[0], b = p4[1];
    part[0]+=a.x; part[1]+=a.y; part[2]+=a.z; part[3]+=a.w;
    part[4]+=b.x; part[5]+=b.y; part[6]+=b.z; part[7]+=b.w;
  }
#pragma unroll
  for (int e = 0; e < 8; e++) {
#pragma unroll
    for (int o = 32; o > 0; o >>= 1) part[e] += __shfl_xor(part[e], o);
  }
  if (lane == 0) {
#pragma unroll
    for (int e = 0; e < 8; e++) wsum[wv][e] = part[e];
  }
  __syncthreads();

  if (t < 8) {
    int running = 0;
    for (int i = 0; i < 256; i++) { int tmp = hist[i][t]; hist[i][t] = running; running += tmp; }
    lcnt[t] = running;
  }
  __syncthreads();
  if (t == 0) {
    int b = 0; float aux = 0.f;
#pragma unroll
    for (int e = 0; e < 8; e++) {
      int ce = lcnt[e];
      bl[e] = b; basep[e] = b; cnt[e] = ce; b += ce;
      float pm = (wsum[0][e]+wsum[1][e]+wsum[2][e]+wsum[3][e]) * (1.f / NTOK);
      aux += pm * logf(pm * 8.f + 1e-9f);
    }
    *aux_out = aux;
  }
  __syncthreads();

#pragma unroll
  for (int i = 0; i < 32; i++) {
    int e = me[i];
    int r = 0;
#pragma unroll
    for (int j = 0; j < i; j++) r += (me[j] == e) ? 1 : 0;
    int slot = bl[e] + hist[t][e] + r;
    int pair = t*32 + i;
    tokenlist[slot] = pair >> 1;
    pairslot[pair] = slot;
  }
}

// ---------------- expert grouped GEMM v3 (r5 champion, twice replay-validated) ----------------
// 128x128, BK=64, static 64KB LDS dbuf, swizzled staging (rule #21), fused asm fence+barrier.
// Grid (x=nt, y=e*32+mt): linear_id%8 = x%8 -> all 32 mt-blocks of a B panel on one XCD.
// MODE 1: Eh = relu(Xg @ We1T + be1)  K=2048 N=4096    MODE 2: Yg = Eh @ We2T + be2  K=4096 N=2048
template<int MODE>
__global__ __launch_bounds__(256, 2) void expert_gemm_v3(
    const unsigned short* __restrict__ Abase,
    const unsigned short* __restrict__ Bbase,   // [E][N][K] bf16
    const float* __restrict__ bias,             // [E][N]
    unsigned short* __restrict__ Cout,          // [slots][N] bf16
    const int* __restrict__ cnt, const int* __restrict__ basep,
    const int* __restrict__ tokenlist)
{
  const int K = (MODE == 1) ? DIM : FDIM;
  const int N = (MODE == 1) ? FDIM : DIM;
  __shared__ char lds[65536];
  int e = blockIdx.y >> 5, mt = blockIdx.y & 31;
  int ne = cnt[e];
  if (mt * 128 >= ne) return;
  int mbase = basep[e] + mt * 128;
  int n0 = blockIdx.x * 128;
  int tid = threadIdx.x, lane = tid & 63, wv = tid >> 6;
  int wm = wv >> 1, wn = wv & 1;

  const char* srcA[4]; const char* srcB[4];
  int sb = (((lane & 7) ^ ((lane >> 3) & 7)) << 4);
#pragma unroll
  for (int i = 0; i < 4; i++) {
    int c = wv + i*4;
    int row = c*8 + (lane >> 3);
    int slot = mbase + row; if (slot > NPAIR - 1) slot = NPAIR - 1;
    size_t arow = (MODE == 1) ? (size_t)tokenlist[slot] : (size_t)slot;
    srcA[i] = (const char*)(Abase + arow * K) + sb;
    srcB[i] = (const char*)(Bbase + ((size_t)e * N + n0 + row) * K) + sb;
  }

  f32x4 acc[4][4];
#pragma unroll
  for (int mb = 0; mb < 4; mb++)
#pragma unroll
    for (int nb = 0; nb < 4; nb++) acc[mb][nb] = (f32x4){0.f,0.f,0.f,0.f};

  // prologue: stage K-tile 0 into buf0
#pragma unroll
  for (int i = 0; i < 4; i++) {
    gl2lds(srcA[i], lds + (wv + i*4)*1024);
    gl2lds(srcB[i], lds + 16384 + (wv + i*4)*1024);
  }
  asm volatile("s_waitcnt vmcnt(0)\n\ts_barrier" ::: "memory");

  const int NT = K / 64;
  int rsw = (lane & 7) << 4;
  int cur = 0;
  for (int kt = 0; kt < NT; kt++) {
    char* cA = lds + cur*32768;
    char* cB = cA + 16384;
    if (kt + 1 < NT) {
      char* nA = lds + (cur^1)*32768;
      char* nB = nA + 16384;
      size_t ko = (size_t)(kt + 1) * 128;
#pragma unroll
      for (int i = 0; i < 4; i++) {
        gl2lds(srcA[i] + ko, nA + (wv + i*4)*1024);
        gl2lds(srcB[i] + ko, nB + (wv + i*4)*1024);
      }
    }
#pragma unroll
    for (int ks = 0; ks < 2; ks++) {
      int kb = (ks*64 + (lane >> 4)*16) ^ rsw;
      s16x8 af[4], bf[4];
#pragma unroll
      for (int mb = 0; mb < 4; mb++)
        af[mb] = *(const s16x8*)(cA + (wm*64 + mb*16 + (lane & 15))*128 + kb);
#pragma unroll
      for (int nb = 0; nb < 4; nb++)
        bf[nb] = *(const s16x8*)(cB + (wn*64 + nb*16 + (lane & 15))*128 + kb);
#pragma unroll
      for (int mb = 0; mb < 4; mb++)
#pragma unroll
        for (int nb = 0; nb < 4; nb++)
          acc[mb][nb] = __builtin_amdgcn_mfma_f32_16x16x32_bf16(af[mb], bf[nb], acc[mb][nb], 0,0,0);
    }
    __builtin_amdgcn_sched_barrier(0);
    asm volatile("s_waitcnt lgkmcnt(0)\n\ts_waitcnt vmcnt(0)\n\ts_barrier" ::: "memory");
    __builtin_amdgcn_sched_barrier(0);
    cur ^= 1;
  }

#pragma unroll
  for (int mb = 0; mb < 4; mb++)
#pragma unroll
    for (int nb = 0; nb < 4; nb++) {
      int col = n0 + wn*64 + nb*16 + (lane & 15);
      float bv = bias[(size_t)e * N + col];
#pragma unroll
      for (int r = 0; r < 4; r++) {
        int mloc = mt*128 + wm*64 + mb*16 + (lane >> 4)*4 + r;
        if (mloc < ne) {
          float v = acc[mb][nb][r] + bv;
          if (MODE == 1) v = fmaxf(v, 0.f);
          Cout[((size_t)basep[e] + mloc) * N + col] = f2bf(v);
        }
      }
    }
}

// ---------------- weighted combine of the two expert outputs per token ----------------
__global__ __launch_bounds__(256) void combine_kernel(
    const unsigned short* __restrict__ Yg, const int* __restrict__ pairslot,
    const float* __restrict__ wts, float* __restrict__ out)
{
  int tok = blockIdx.x, tid = threadIdx.x;
  int s0 = pairslot[tok*2], s1 = pairslot[tok*2+1];
  float w0 = wts[tok*2], w1 = wts[tok*2+1];
  s16x8 a = *(const s16x8*)(Yg + (size_t)s0 * DIM + tid*8);
  s16x8 b = *(const s16x8*)(Yg + (size_t)s1 * DIM + tid*8);
  float o[8];
#pragma unroll
  for (int j = 0; j < 8; j++)
    o[j] = w0 * bf2f((unsigned short)a[j]) + w1 * bf2f((unsigned short)b[j]);
  float* op = out + (size_t)tok * DIM + tid*8;
  float4 o0; o0.x=o[0]; o0.y=o[1]; o0.z=o[2]; o0.w=o[3];
  float4 o1; o1.x=o[4]; o1.y=o[5]; o1.z=o[6]; o1.w=o[7];
  *(float4*)op = o0;
  *(float4*)(op + 4) = o1;
}

// ---------------- host launcher ----------------
extern "C" void kernel_launch(void* const* d_in, const int* in_sizes, int n_in,
                              void* d_out, int out_size, void* d_ws, size_t ws_size,
                              hipStream_t stream)
{
  (void)in_sizes; (void)n_in; (void)out_size; (void)ws_size;
  const float* x    = (const float*)d_in[0];
  const float* ln_g = (const float*)d_in[1];
  const float* ln_b = (const float*)d_in[2];
  const float* rW1  = (const float*)d_in[3];
  const float* rb1  = (const float*)d_in[4];
  const float* rW2  = (const float*)d_in[5];
  const float* rb2  = (const float*)d_in[6];
  const float* We1  = (const float*)d_in[7];
  const float* be1  = (const float*)d_in[8];
  const float* We2  = (const float*)d_in[9];
  const float* be2  = (const float*)d_in[10];
  float* out = (float*)d_out;
  float* aux_out = out + (size_t)NTOK * DIM;

  char* ws = (char*)d_ws;
  size_t off = 0;
  auto alloc = [&](size_t bytes) { char* p = ws + off; off += (bytes + 255) & ~(size_t)255; return p; };

  _Float16* XH   = (_Float16*)alloc((size_t)NTOK * DIM * 2);
  _Float16* XL   = (_Float16*)alloc((size_t)NTOK * DIM * 2);
  unsigned short* XBF = (unsigned short*)alloc((size_t)NTOK * DIM * 2);
  _Float16* RW1H = (_Float16*)alloc((size_t)DIM * DIM * 2);
  _Float16* RW1L = (_Float16*)alloc((size_t)DIM * DIM * 2);
  unsigned short* WET = (unsigned short*)alloc((size_t)NEXP * FDIM * DIM * 2); // We1T then We2T
  unsigned short* EH  = (unsigned short*)alloc((size_t)(NPAIR + 128) * FDIM * 2);
  char* HY = alloc((size_t)(NPAIR + 128) * DIM * 2 > (size_t)NTOK*DIM*4
                     ? (size_t)(NPAIR + 128) * DIM * 2 : (size_t)NTOK*DIM*4);
  float* H = (float*)HY;                 // router hidden, dead before YG is written
  unsigned short* YG = (unsigned short*)HY;
  float* PROB = (float*)alloc((size_t)NTOK * 8 * 4);
  int* CNT  = (int*)alloc(256);
  int* BASE = CNT + 16;
  int* EID  = (int*)alloc((size_t)NPAIR * 4);
  float* WTS = (float*)alloc((size_t)NPAIR * 4);
  int* PAIRSLOT = (int*)alloc((size_t)NPAIR * 4);
  int* TOKLIST  = (int*)alloc((size_t)(NPAIR + 128) * 4);

  ln_conv_kernel<<<NTOK, 256, 0, stream>>>(x, ln_g, ln_b, XH, XL, XBF);
  transpose_f16split_kernel<<<dim3(DIM/64, DIM/64), 256, 0, stream>>>(rW1, RW1H, RW1L, DIM, DIM);
  // We1 [E][D][F] -> We1T [E][F][D]
  transpose_bf16_kernel<<<dim3(FDIM/64, DIM/64, NEXP), 256, 0, stream>>>(We1, WET, DIM, FDIM);
  router_gemm_kernel<<<dim3(DIM/64, NTOK/128), 256, 0, stream>>>(XH, XL, RW1H, RW1L, rb1, H);
  router_logits_kernel<<<NTOK/4, 256, 0, stream>>>(H, rW2, rb2, PROB, EID, WTS);
  router_sort_kernel<<<1, 256, 0, stream>>>(EID, PROB, CNT, BASE, TOKLIST, PAIRSLOT, aux_out);
  expert_gemm_v3<1><<<dim3(FDIM/128, NEXP*32), 256, 0, stream>>>(XBF, WET, be1, EH, CNT, BASE, TOKLIST);
  // We2 [E][F][D] -> We2T [E][D][F]  (reuses WET after GEMM1 is done)
  transpose_bf16_kernel<<<dim3(DIM/64, FDIM/64, NEXP), 256, 0, stream>>>(We2, WET, FDIM, DIM);
  expert_gemm_v3<2><<<dim3(DIM/128, NEXP*32), 256, 0, stream>>>(EH, WET, be2, YG, CNT, BASE, TOKLIST);
  combine_kernel<<<NTOK, 256, 0, stream>>>(YG, PAIRSLOT, WTS, out);
}